// Round 3
// baseline (154.139 us; speedup 1.0000x reference)
//
#include <hip/hip_runtime.h>
#include <hip/hip_fp16.h>

// SIREN, single fused kernel, fully register-resident, 128 points/wave.
// A=weights / B=activations: D[16 feat x 16 pt] = W[16,32] * X[32,16 pt].
// sigma(p)=16*((p>>2)&1)+4*(p>>3)+(p&3) k-permutation makes each lane's packed
// sin outputs BE the next layer's B-fragment (no LDS, no shuffles in the loop).
// sigma(8q+j) = {4q+j (j<4), 16+4q+(j-4) (j>=4)} -> a lane's A-fragment is two
// aligned float4 loads from the raw weight matrix, packed with v_cvt_pkrtz.
// Weights single f16 (hi-only): adds ~2e-3 error, far under the 1.6e-2
// threshold. 30/(2pi) folded into weights/biases at load time.
//
// R14: REGISTER-BUDGET FIX. R0-R12 all allocated VGPR=64 (backend squeezed to
// an 8-wave schedule), which CANNOT hold Af frags(36)+Bt(32)+L0 consts(24):
// the compiler was re-loading weight frags from L2 every layer and
// serializing every t-chain; identical convoying waves left the VALU port
// 32% idle (VALUBusy 68%, occupancy ~2.75 waves/SIMD measured).
// amdgpu_waves_per_eu(2,3) raises the VGPR cap to ~170 AND stops the
// scheduler from trading ILP for occupancy the HW never achieved. Middle
// layers are phase-split (16 MFMAs batched -> 64 sins) so 8 independent
// chains cover MFMA/sin latency. R2's persistent-wave experiment regressed
// (store/fetch amplification) and is reverted: 1 tile per wave, 4096 blocks.

#define SINSCALE 4.774648292756860f   // 30/(2*pi)

typedef __attribute__((ext_vector_type(8))) _Float16 half8;
typedef __attribute__((ext_vector_type(2))) __fp16 fp16x2;
typedef __attribute__((ext_vector_type(4))) float f32x4;

union S16 { uint4 u4; half8 h; };
union PK { fp16x2 h2; unsigned int u; };

__device__ __forceinline__ float fast_sigmoid(float t) {
    float e = __builtin_amdgcn_exp2f(t * -1.4426950408889634f);
    return 1.0f / (1.0f + e);
}

__device__ __forceinline__ unsigned int pk2(float a, float b) {
    PK p; p.h2 = __builtin_amdgcn_cvt_pkrtz(a, b);
    return p.u;
}

// Build the sigma-permuted A-fragment (hi f16, RTZ) for feature rows m:
// slots j=0..3 <- W[m][4q+j]*S, j=4..7 <- W[m][16+4q+(j-4)]*S.
__device__ __forceinline__ uint4 build_frag(const float* __restrict__ W, int m, int q) {
    const float4 fa = *reinterpret_cast<const float4*>(&W[m * 32 + 4 * q]);
    const float4 fb = *reinterpret_cast<const float4*>(&W[m * 32 + 16 + 4 * q]);
    uint4 u;
    u.x = pk2(fa.x * SINSCALE, fa.y * SINSCALE);
    u.y = pk2(fa.z * SINSCALE, fa.w * SINSCALE);
    u.z = pk2(fb.x * SINSCALE, fb.y * SINSCALE);
    u.w = pk2(fb.z * SINSCALE, fb.w * SINSCALE);
    return u;
}

// Scaled bias vector for C/D rows 4q..4q+3 (+off)
__device__ __forceinline__ f32x4 bias_frag(const float* __restrict__ b, int off, int q) {
    const float4 t = *reinterpret_cast<const float4*>(&b[off + 4 * q]);
    f32x4 r = {t.x * SINSCALE, t.y * SINSCALE, t.z * SINSCALE, t.w * SINSCALE};
    return r;
}

__global__
__attribute__((amdgpu_flat_work_group_size(256, 256), amdgpu_waves_per_eu(2, 3)))
void siren_mfma(
    const float* __restrict__ coords,
    const float* __restrict__ w0, const float* __restrict__ b0,
    const float* __restrict__ w1, const float* __restrict__ b1,
    const float* __restrict__ w2, const float* __restrict__ b2,
    const float* __restrict__ w3, const float* __restrict__ b3,
    const float* __restrict__ w4, const float* __restrict__ b4,
    const float* __restrict__ w5, const float* __restrict__ b5,
    const float* __restrict__ wf, const float* __restrict__ bfin,
    float* __restrict__ out, int n) {
    const int lane = (int)(threadIdx.x & 63);
    const int q = lane >> 4;
    const int nl = lane & 15;
    const int pbase = blockIdx.x * 512 + (int)(threadIdx.x >> 6) * 128;

    // ---- hoist ALL coord loads: 8 independent global_load_dwordx2 in flight
    float2 cxy[8];
#pragma unroll
    for (int t = 0; t < 8; ++t) {
        int ptc = min(pbase + 16 * t + nl, n - 1);
        cxy[t] = reinterpret_cast<const float2*>(coords)[ptc];
    }

    // ---- weight fragments for layers 1..5 (kept LIVE across all layers) ----
    uint4 Af[4][2];
    Af[0][0] = build_frag(w1, nl, q);  Af[0][1] = build_frag(w1, 16 + nl, q);
    Af[1][0] = build_frag(w2, nl, q);  Af[1][1] = build_frag(w2, 16 + nl, q);
    Af[2][0] = build_frag(w3, nl, q);  Af[2][1] = build_frag(w3, 16 + nl, q);
    Af[3][0] = build_frag(w4, nl, q);  Af[3][1] = build_frag(w4, 16 + nl, q);
    const uint4 Af5 = build_frag(w5, nl, q);

    // ---- L0: 2 -> 32 directly in B-frag format (features sigma(8q+j)) ----
    const float4 wa = *reinterpret_cast<const float4*>(&w0[8 * q]);
    const float4 wb = *reinterpret_cast<const float4*>(&w0[8 * q + 4]);
    const float4 wc = *reinterpret_cast<const float4*>(&w0[32 + 8 * q]);
    const float4 wd = *reinterpret_cast<const float4*>(&w0[32 + 8 * q + 4]);
    const float4 ba = *reinterpret_cast<const float4*>(&b0[4 * q]);
    const float4 bc = *reinterpret_cast<const float4*>(&b0[16 + 4 * q]);
    float wxs[8] = {wa.x, wa.z, wb.x, wb.z, wc.x, wc.z, wd.x, wd.z};
    float wys[8] = {wa.y, wa.w, wb.y, wb.w, wc.y, wc.w, wd.y, wd.w};
    float bbs[8] = {ba.x, ba.y, ba.z, ba.w, bc.x, bc.y, bc.z, bc.w};
#pragma unroll
    for (int j = 0; j < 8; ++j) {
        wxs[j] *= SINSCALE;
        wys[j] *= SINSCALE;
        bbs[j] *= SINSCALE;
    }

    uint4 Bt[8];
#pragma unroll
    for (int t = 0; t < 8; ++t) {
        float s[8];
#pragma unroll
        for (int j = 0; j < 8; ++j)
            s[j] = __builtin_amdgcn_sinf(fmaf(wxs[j], cxy[t].x, fmaf(wys[j], cxy[t].y, bbs[j])));
        Bt[t].x = pk2(s[0], s[1]);
        Bt[t].y = pk2(s[2], s[3]);
        Bt[t].z = pk2(s[4], s[5]);
        Bt[t].w = pk2(s[6], s[7]);
    }

    // ---- middle layers 1..4: phase-split. All 16 MFMAs first (8 independent
    // t-chains in the matrix pipe), then all 64 sins (trans pipe), then packs.
    const float* Bs[4] = {b1, b2, b3, b4};
#pragma unroll
    for (int l = 0; l < 4; ++l) {
        S16 Ah0, Ah1;
        Ah0.u4 = Af[l][0];
        Ah1.u4 = Af[l][1];
        const f32x4 bv0 = bias_frag(Bs[l], 0, q);
        const f32x4 bv1 = bias_frag(Bs[l], 16, q);
        f32x4 c0[8], c1[8];
#pragma unroll
        for (int t = 0; t < 8; ++t) {
            S16 B;
            B.u4 = Bt[t];
            c0[t] = __builtin_amdgcn_mfma_f32_16x16x32_f16(Ah0.h, B.h, bv0, 0, 0, 0);
            c1[t] = __builtin_amdgcn_mfma_f32_16x16x32_f16(Ah1.h, B.h, bv1, 0, 0, 0);
        }
#pragma unroll
        for (int t = 0; t < 8; ++t) {
            Bt[t].x = pk2(__builtin_amdgcn_sinf(c0[t][0]), __builtin_amdgcn_sinf(c0[t][1]));
            Bt[t].y = pk2(__builtin_amdgcn_sinf(c0[t][2]), __builtin_amdgcn_sinf(c0[t][3]));
            Bt[t].z = pk2(__builtin_amdgcn_sinf(c1[t][0]), __builtin_amdgcn_sinf(c1[t][1]));
            Bt[t].w = pk2(__builtin_amdgcn_sinf(c1[t][2]), __builtin_amdgcn_sinf(c1[t][3]));
        }
    }

    // ---- L5 (32->16) + final (16->3): phase-split MFMA / sin / reduce ----
    {
        S16 Ah5;
        Ah5.u4 = Af5;
        const f32x4 bv5 = bias_frag(b5, 0, q);
        float4 wfl[3];
#pragma unroll
        for (int c = 0; c < 3; ++c)
            wfl[c] = *reinterpret_cast<const float4*>(&wf[c * 16 + 4 * q]);

        f32x4 c5[8];
#pragma unroll
        for (int t = 0; t < 8; ++t) {
            S16 B;
            B.u4 = Bt[t];
            c5[t] = __builtin_amdgcn_mfma_f32_16x16x32_f16(Ah5.h, B.h, bv5, 0, 0, 0);
        }

        float red[8][3];
#pragma unroll
        for (int t = 0; t < 8; ++t) {
            float h0 = __builtin_amdgcn_sinf(c5[t][0]);
            float h1 = __builtin_amdgcn_sinf(c5[t][1]);
            float h2 = __builtin_amdgcn_sinf(c5[t][2]);
            float h3 = __builtin_amdgcn_sinf(c5[t][3]);
#pragma unroll
            for (int c = 0; c < 3; ++c)
                red[t][c] = fmaf(wfl[c].x, h0, fmaf(wfl[c].y, h1,
                            fmaf(wfl[c].z, h2, wfl[c].w * h3)));
        }
        // butterfly over the 4 q-lanes sharing a point column
#pragma unroll
        for (int t = 0; t < 8; ++t)
#pragma unroll
            for (int c = 0; c < 3; ++c) {
                float v = red[t][c];
                v += __shfl_xor(v, 16, 64);
                v += __shfl_xor(v, 32, 64);
                red[t][c] = v;
            }
        // lane outputs two points: t=q (pts 0..63) and t=4+q (pts 64..127)
        float o0[3], o1[3];
#pragma unroll
        for (int c = 0; c < 3; ++c) {
            float v01 = (q & 1) ? red[1][c] : red[0][c];
            float v23 = (q & 1) ? red[3][c] : red[2][c];
            o0[c] = fast_sigmoid(((q & 2) ? v23 : v01) + bfin[c]);
            float w01 = (q & 1) ? red[5][c] : red[4][c];
            float w23 = (q & 1) ? red[7][c] : red[6][c];
            o1[c] = fast_sigmoid(((q & 2) ? w23 : w01) + bfin[c]);
        }
        const int p0 = pbase + 16 * q + nl;
        const int p1 = p0 + 64;
        if (p0 < n) {
            out[3 * p0 + 0] = o0[0];
            out[3 * p0 + 1] = o0[1];
            out[3 * p0 + 2] = o0[2];
        }
        if (p1 < n) {
            out[3 * p1 + 0] = o1[0];
            out[3 * p1 + 1] = o1[1];
            out[3 * p1 + 2] = o1[2];
        }
    }
}

extern "C" void kernel_launch(void* const* d_in, const int* in_sizes, int n_in,
                              void* d_out, int out_size, void* d_ws, size_t ws_size,
                              hipStream_t stream) {
    const float* coords = (const float*)d_in[0];
    const float* w0 = (const float*)d_in[1];
    const float* b0 = (const float*)d_in[2];
    const float* w1 = (const float*)d_in[3];
    const float* b1 = (const float*)d_in[4];
    const float* w2 = (const float*)d_in[5];
    const float* b2 = (const float*)d_in[6];
    const float* w3 = (const float*)d_in[7];
    const float* b3 = (const float*)d_in[8];
    const float* w4 = (const float*)d_in[9];
    const float* b4 = (const float*)d_in[10];
    const float* w5 = (const float*)d_in[11];
    const float* b5 = (const float*)d_in[12];
    const float* wf = (const float*)d_in[13];
    const float* bf = (const float*)d_in[14];
    float* out = (float*)d_out;

    const int n = in_sizes[0] / 2;

    siren_mfma<<<(n + 511) / 512, 256, 0, stream>>>(
        coords, w0, b0, w1, b1, w2, b2, w3, b3, w4, b4, w5, b5, wf, bf, out, n);
}

// Round 4
// 147.673 us; speedup vs baseline: 1.0438x; 1.0438x over previous
//
#include <hip/hip_runtime.h>
#include <hip/hip_fp16.h>

// SIREN, single fused kernel, register+LDS-resident, 128 points/wave.
// A=weights / B=activations: D[16 feat x 16 pt] = W[16,32] * X[32,16 pt].
// sigma(p)=16*((p>>2)&1)+4*(p>>3)+(p&3) k-permutation makes each lane's packed
// sin outputs BE the next layer's B-fragment (no shuffles in the loop).
// sigma(8q+j) = {4q+j (j<4), 16+4q+(j-4) (j>=4)} -> a lane's A-fragment is two
// aligned float4 loads from the raw weight matrix, packed with v_cvt_pkrtz.
// Weights single f16 (hi-only): adds ~2e-3 error, far under the 1.6e-2
// threshold. 30/(2pi) folded into weights/biases at load time.
//
// R15: LDS WEIGHT TABLE. Evidence chain: VGPR=64/68 across all attempts even
// with a 170-reg budget (R3) => the allocator REFUSES to keep Af(36)+Bt(32)
// live and re-loads A-frags + biases from L2 (~300cy) inside every layer; all
// waves convoy through these vmcnt waits => the measured 32% VALU-idle. R3
// also showed dur scales ~1/occupancy, so VGPR-pinning (which costs waves) is
// the wrong fix. Instead each wave builds its per-lane frags ONCE and parks
// them in a conflict-free LDS table ([slot][lane], lane-contiguous 16B); each
// layer re-fetches via hoistable ds_read_b128 (no vmcnt, ~120cy). No barrier:
// every wave reads only what its own lanes wrote (identical-value races from
// sibling waves are benign). Register pressure = baseline => occupancy kept.
// Coords + L0 consts load BEFORE the build so VMEM latency hides under pack
// work. One asm memory clobber stops write->read forwarding back into regs.

#define SINSCALE 4.774648292756860f   // 30/(2*pi)

typedef __attribute__((ext_vector_type(8))) _Float16 half8;
typedef __attribute__((ext_vector_type(2))) __fp16 fp16x2;
typedef __attribute__((ext_vector_type(4))) float f32x4;

union S16 { uint4 u4; half8 h; };
union PK { fp16x2 h2; unsigned int u; };
union WU { uint4 u; f32x4 f; float4 f4; };

__device__ __forceinline__ float fast_sigmoid(float t) {
    float e = __builtin_amdgcn_exp2f(t * -1.4426950408889634f);
    return 1.0f / (1.0f + e);
}

__device__ __forceinline__ unsigned int pk2(float a, float b) {
    PK p; p.h2 = __builtin_amdgcn_cvt_pkrtz(a, b);
    return p.u;
}

// Build the sigma-permuted A-fragment (hi f16, RTZ) for feature rows m:
// slots j=0..3 <- W[m][4q+j]*S, j=4..7 <- W[m][16+4q+(j-4)]*S.
__device__ __forceinline__ uint4 build_frag(const float* __restrict__ W, int m, int q) {
    const float4 fa = *reinterpret_cast<const float4*>(&W[m * 32 + 4 * q]);
    const float4 fb = *reinterpret_cast<const float4*>(&W[m * 32 + 16 + 4 * q]);
    uint4 u;
    u.x = pk2(fa.x * SINSCALE, fa.y * SINSCALE);
    u.y = pk2(fa.z * SINSCALE, fa.w * SINSCALE);
    u.z = pk2(fb.x * SINSCALE, fb.y * SINSCALE);
    u.w = pk2(fb.z * SINSCALE, fb.w * SINSCALE);
    return u;
}

// Scaled bias vector (bit-pattern) for C/D rows 4q..4q+3 (+off)
__device__ __forceinline__ uint4 bias_frag_u(const float* __restrict__ b, int off, int q) {
    const float4 t = *reinterpret_cast<const float4*>(&b[off + 4 * q]);
    WU w;
    w.f = (f32x4){t.x * SINSCALE, t.y * SINSCALE, t.z * SINSCALE, t.w * SINSCALE};
    return w.u;
}

// LDS table slots: 0..7 = Af[layer][half] (2l+h), 8 = Af5,
// 9..16 = bv0/bv1 per layer (9+2l, 10+2l), 17 = bv5, 18..20 = wfl[c] (raw).
__global__ __launch_bounds__(256, 3) void siren_mfma(
    const float* __restrict__ coords,
    const float* __restrict__ w0, const float* __restrict__ b0,
    const float* __restrict__ w1, const float* __restrict__ b1,
    const float* __restrict__ w2, const float* __restrict__ b2,
    const float* __restrict__ w3, const float* __restrict__ b3,
    const float* __restrict__ w4, const float* __restrict__ b4,
    const float* __restrict__ w5, const float* __restrict__ b5,
    const float* __restrict__ wf, const float* __restrict__ bfin,
    float* __restrict__ out, int n) {
    const int lane = (int)(threadIdx.x & 63);
    const int q = lane >> 4;
    const int nl = lane & 15;
    const int pbase = blockIdx.x * 512 + (int)(threadIdx.x >> 6) * 128;

    __shared__ uint4 wtab[21][64];

    // ---- coords first: 8 independent global_load_dwordx2 in flight early
    float2 cxy[8];
#pragma unroll
    for (int t = 0; t < 8; ++t) {
        int ptc = min(pbase + 16 * t + nl, n - 1);
        cxy[t] = reinterpret_cast<const float2*>(coords)[ptc];
    }

    // ---- L0 constants (2 -> 32 in B-frag feature order sigma(8q+j)) ----
    const float4 wa = *reinterpret_cast<const float4*>(&w0[8 * q]);
    const float4 wb = *reinterpret_cast<const float4*>(&w0[8 * q + 4]);
    const float4 wc = *reinterpret_cast<const float4*>(&w0[32 + 8 * q]);
    const float4 wd = *reinterpret_cast<const float4*>(&w0[32 + 8 * q + 4]);
    const float4 ba = *reinterpret_cast<const float4*>(&b0[4 * q]);
    const float4 bc = *reinterpret_cast<const float4*>(&b0[16 + 4 * q]);
    float wxs[8] = {wa.x, wa.z, wb.x, wb.z, wc.x, wc.z, wd.x, wd.z};
    float wys[8] = {wa.y, wa.w, wb.y, wb.w, wc.y, wc.w, wd.y, wd.w};
    float bbs[8] = {ba.x, ba.y, ba.z, ba.w, bc.x, bc.y, bc.z, bc.w};
#pragma unroll
    for (int j = 0; j < 8; ++j) {
        wxs[j] *= SINSCALE;
        wys[j] *= SINSCALE;
        bbs[j] *= SINSCALE;
    }

    // ---- build per-lane fragment table into LDS (once per wave) ----
    wtab[0][lane] = build_frag(w1, nl, q);
    wtab[1][lane] = build_frag(w1, 16 + nl, q);
    wtab[2][lane] = build_frag(w2, nl, q);
    wtab[3][lane] = build_frag(w2, 16 + nl, q);
    wtab[4][lane] = build_frag(w3, nl, q);
    wtab[5][lane] = build_frag(w3, 16 + nl, q);
    wtab[6][lane] = build_frag(w4, nl, q);
    wtab[7][lane] = build_frag(w4, 16 + nl, q);
    wtab[8][lane] = build_frag(w5, nl, q);
    wtab[9][lane]  = bias_frag_u(b1, 0, q);
    wtab[10][lane] = bias_frag_u(b1, 16, q);
    wtab[11][lane] = bias_frag_u(b2, 0, q);
    wtab[12][lane] = bias_frag_u(b2, 16, q);
    wtab[13][lane] = bias_frag_u(b3, 0, q);
    wtab[14][lane] = bias_frag_u(b3, 16, q);
    wtab[15][lane] = bias_frag_u(b4, 0, q);
    wtab[16][lane] = bias_frag_u(b4, 16, q);
    wtab[17][lane] = bias_frag_u(b5, 0, q);
    wtab[18][lane] = *reinterpret_cast<const uint4*>(&wf[0 * 16 + 4 * q]);
    wtab[19][lane] = *reinterpret_cast<const uint4*>(&wf[1 * 16 + 4 * q]);
    wtab[20][lane] = *reinterpret_cast<const uint4*>(&wf[2 * 16 + 4 * q]);

    // stop the compiler from forwarding LDS writes back into registers
    asm volatile("" ::: "memory");

    // ---- L0: sin(w0x*x + w0y*y + b0) in B-frag layout ----
    uint4 Bt[8];
#pragma unroll
    for (int t = 0; t < 8; ++t) {
        float s[8];
#pragma unroll
        for (int j = 0; j < 8; ++j)
            s[j] = __builtin_amdgcn_sinf(fmaf(wxs[j], cxy[t].x, fmaf(wys[j], cxy[t].y, bbs[j])));
        Bt[t].x = pk2(s[0], s[1]);
        Bt[t].y = pk2(s[2], s[3]);
        Bt[t].z = pk2(s[4], s[5]);
        Bt[t].w = pk2(s[6], s[7]);
    }

    // ---- middle layers 1..4: A-frags + biases from LDS (ds_read_b128) ----
#pragma unroll
    for (int l = 0; l < 4; ++l) {
        S16 Ah0, Ah1;
        Ah0.u4 = wtab[2 * l][lane];
        Ah1.u4 = wtab[2 * l + 1][lane];
        WU bw0, bw1;
        bw0.u = wtab[9 + 2 * l][lane];
        bw1.u = wtab[10 + 2 * l][lane];
        const f32x4 bv0 = bw0.f;
        const f32x4 bv1 = bw1.f;
#pragma unroll
        for (int t = 0; t < 8; ++t) {
            S16 B;
            B.u4 = Bt[t];
            f32x4 c0 = __builtin_amdgcn_mfma_f32_16x16x32_f16(Ah0.h, B.h, bv0, 0, 0, 0);
            f32x4 c1 = __builtin_amdgcn_mfma_f32_16x16x32_f16(Ah1.h, B.h, bv1, 0, 0, 0);
            Bt[t].x = pk2(__builtin_amdgcn_sinf(c0[0]), __builtin_amdgcn_sinf(c0[1]));
            Bt[t].y = pk2(__builtin_amdgcn_sinf(c0[2]), __builtin_amdgcn_sinf(c0[3]));
            Bt[t].z = pk2(__builtin_amdgcn_sinf(c1[0]), __builtin_amdgcn_sinf(c1[1]));
            Bt[t].w = pk2(__builtin_amdgcn_sinf(c1[2]), __builtin_amdgcn_sinf(c1[3]));
        }
    }

    // ---- L5 (32->16) + final (16->3): registers + shfl butterfly ----
    {
        S16 Ah5;
        Ah5.u4 = wtab[8][lane];
        WU bw5;
        bw5.u = wtab[17][lane];
        const f32x4 bv5 = bw5.f;
        float4 wfl[3];
#pragma unroll
        for (int c = 0; c < 3; ++c) {
            WU w;
            w.u = wtab[18 + c][lane];
            wfl[c] = w.f4;
        }

        float red[8][3];
#pragma unroll
        for (int t = 0; t < 8; ++t) {
            S16 B;
            B.u4 = Bt[t];
            f32x4 c5 = __builtin_amdgcn_mfma_f32_16x16x32_f16(Ah5.h, B.h, bv5, 0, 0, 0);
            float h0 = __builtin_amdgcn_sinf(c5[0]);
            float h1 = __builtin_amdgcn_sinf(c5[1]);
            float h2 = __builtin_amdgcn_sinf(c5[2]);
            float h3 = __builtin_amdgcn_sinf(c5[3]);
#pragma unroll
            for (int c = 0; c < 3; ++c)
                red[t][c] = fmaf(wfl[c].x, h0, fmaf(wfl[c].y, h1,
                            fmaf(wfl[c].z, h2, wfl[c].w * h3)));
        }
        // butterfly over the 4 q-lanes sharing a point column
#pragma unroll
        for (int t = 0; t < 8; ++t)
#pragma unroll
            for (int c = 0; c < 3; ++c) {
                float v = red[t][c];
                v += __shfl_xor(v, 16, 64);
                v += __shfl_xor(v, 32, 64);
                red[t][c] = v;
            }
        // lane outputs two points: t=q (pts 0..63) and t=4+q (pts 64..127)
        float o0[3], o1[3];
#pragma unroll
        for (int c = 0; c < 3; ++c) {
            float v01 = (q & 1) ? red[1][c] : red[0][c];
            float v23 = (q & 1) ? red[3][c] : red[2][c];
            o0[c] = fast_sigmoid(((q & 2) ? v23 : v01) + bfin[c]);
            float w01 = (q & 1) ? red[5][c] : red[4][c];
            float w23 = (q & 1) ? red[7][c] : red[6][c];
            o1[c] = fast_sigmoid(((q & 2) ? w23 : w01) + bfin[c]);
        }
        const int p0 = pbase + 16 * q + nl;
        const int p1 = p0 + 64;
        if (p0 < n) {
            out[3 * p0 + 0] = o0[0];
            out[3 * p0 + 1] = o0[1];
            out[3 * p0 + 2] = o0[2];
        }
        if (p1 < n) {
            out[3 * p1 + 0] = o1[0];
            out[3 * p1 + 1] = o1[1];
            out[3 * p1 + 2] = o1[2];
        }
    }
}

extern "C" void kernel_launch(void* const* d_in, const int* in_sizes, int n_in,
                              void* d_out, int out_size, void* d_ws, size_t ws_size,
                              hipStream_t stream) {
    const float* coords = (const float*)d_in[0];
    const float* w0 = (const float*)d_in[1];
    const float* b0 = (const float*)d_in[2];
    const float* w1 = (const float*)d_in[3];
    const float* b1 = (const float*)d_in[4];
    const float* w2 = (const float*)d_in[5];
    const float* b2 = (const float*)d_in[6];
    const float* w3 = (const float*)d_in[7];
    const float* b3 = (const float*)d_in[8];
    const float* w4 = (const float*)d_in[9];
    const float* b4 = (const float*)d_in[10];
    const float* w5 = (const float*)d_in[11];
    const float* b5 = (const float*)d_in[12];
    const float* wf = (const float*)d_in[13];
    const float* bf = (const float*)d_in[14];
    float* out = (float*)d_out;

    const int n = in_sizes[0] / 2;

    siren_mfma<<<(n + 511) / 512, 256, 0, stream>>>(
        coords, w0, b0, w1, b1, w2, b2, w3, b3, w4, b4, w5, b5, wf, bf, out, n);
}

// Round 5
// 144.239 us; speedup vs baseline: 1.0686x; 1.0238x over previous
//
#include <hip/hip_runtime.h>
#include <hip/hip_fp16.h>

// SIREN, single fused kernel, register+LDS-resident, 128 points/wave.
// A=weights / B=activations: D[16 feat x 16 pt] = W[16,32] * X[32,16 pt].
// sigma(p)=16*((p>>2)&1)+4*(p>>3)+(p&3) k-permutation makes each lane's packed
// sin outputs BE the next layer's B-fragment (no shuffles in the loop).
// sigma(8q+j) = {4q+j (j<4), 16+4q+(j-4) (j>=4)} -> a lane's A-fragment is two
// aligned float4 loads from the raw weight matrix, packed with v_cvt_pkrtz.
// Weights single f16 (hi-only): adds ~2e-3 error, far under the 1.6e-2
// threshold. 30/(2pi) folded into weights/biases at load time.
//
// R16: FORCED PHASE-SPLIT via sched_barrier(0). Evidence: VALU busy TIME is
// invariant (~40-41us) across R0/R3/R4 while stalls moved 19->24us; per-wave
// math gives ~13.5cy/sin with sins = 75% of issue work. The stall component
// is in-order issue down a serial t-chain (MFMA->sins->pack->next MFMA): the
// machine scheduler collapsed every source-level phase-split (R12) back to
// the low-pressure serial form. sched_barrier(0) runs BEFORE regalloc and
// makes the collapse illegal: 16 MFMAs cluster (latencies overlap), 64
// independent sins pipeline at trans throughput, c0/c1 materialize (VGPR
// ~130, still 3-4 waves/SIMD with the R15 LDS weight table), and A-frags get
// short live ranges. Next layer's ds_reads float up into the sin region so
// lgkmcnt hides under sins. L0 (args->SB->sins) and L5 (MFMA->SB->sins) get
// the same treatment.

#define SINSCALE 4.774648292756860f   // 30/(2*pi)

typedef __attribute__((ext_vector_type(8))) _Float16 half8;
typedef __attribute__((ext_vector_type(2))) __fp16 fp16x2;
typedef __attribute__((ext_vector_type(4))) float f32x4;

union S16 { uint4 u4; half8 h; };
union PK { fp16x2 h2; unsigned int u; };
union WU { uint4 u; f32x4 f; float4 f4; };

__device__ __forceinline__ float fast_sigmoid(float t) {
    float e = __builtin_amdgcn_exp2f(t * -1.4426950408889634f);
    return 1.0f / (1.0f + e);
}

__device__ __forceinline__ unsigned int pk2(float a, float b) {
    PK p; p.h2 = __builtin_amdgcn_cvt_pkrtz(a, b);
    return p.u;
}

// Build the sigma-permuted A-fragment (hi f16, RTZ) for feature rows m:
// slots j=0..3 <- W[m][4q+j]*S, j=4..7 <- W[m][16+4q+(j-4)]*S.
__device__ __forceinline__ uint4 build_frag(const float* __restrict__ W, int m, int q) {
    const float4 fa = *reinterpret_cast<const float4*>(&W[m * 32 + 4 * q]);
    const float4 fb = *reinterpret_cast<const float4*>(&W[m * 32 + 16 + 4 * q]);
    uint4 u;
    u.x = pk2(fa.x * SINSCALE, fa.y * SINSCALE);
    u.y = pk2(fa.z * SINSCALE, fa.w * SINSCALE);
    u.z = pk2(fb.x * SINSCALE, fb.y * SINSCALE);
    u.w = pk2(fb.z * SINSCALE, fb.w * SINSCALE);
    return u;
}

// Scaled bias vector (bit-pattern) for C/D rows 4q..4q+3 (+off)
__device__ __forceinline__ uint4 bias_frag_u(const float* __restrict__ b, int off, int q) {
    const float4 t = *reinterpret_cast<const float4*>(&b[off + 4 * q]);
    WU w;
    w.f = (f32x4){t.x * SINSCALE, t.y * SINSCALE, t.z * SINSCALE, t.w * SINSCALE};
    return w.u;
}

// LDS table slots: 0..7 = Af[layer][half] (2l+h), 8 = Af5,
// 9..16 = bv0/bv1 per layer (9+2l, 10+2l), 17 = bv5, 18..20 = wfl[c] (raw).
__global__ __launch_bounds__(256, 3) void siren_mfma(
    const float* __restrict__ coords,
    const float* __restrict__ w0, const float* __restrict__ b0,
    const float* __restrict__ w1, const float* __restrict__ b1,
    const float* __restrict__ w2, const float* __restrict__ b2,
    const float* __restrict__ w3, const float* __restrict__ b3,
    const float* __restrict__ w4, const float* __restrict__ b4,
    const float* __restrict__ w5, const float* __restrict__ b5,
    const float* __restrict__ wf, const float* __restrict__ bfin,
    float* __restrict__ out, int n) {
    const int lane = (int)(threadIdx.x & 63);
    const int q = lane >> 4;
    const int nl = lane & 15;
    const int pbase = blockIdx.x * 512 + (int)(threadIdx.x >> 6) * 128;

    __shared__ uint4 wtab[21][64];

    // ---- coords first: 8 independent global_load_dwordx2 in flight early
    float2 cxy[8];
#pragma unroll
    for (int t = 0; t < 8; ++t) {
        int ptc = min(pbase + 16 * t + nl, n - 1);
        cxy[t] = reinterpret_cast<const float2*>(coords)[ptc];
    }

    // ---- L0 constants (2 -> 32 in B-frag feature order sigma(8q+j)) ----
    const float4 wa = *reinterpret_cast<const float4*>(&w0[8 * q]);
    const float4 wb = *reinterpret_cast<const float4*>(&w0[8 * q + 4]);
    const float4 wc = *reinterpret_cast<const float4*>(&w0[32 + 8 * q]);
    const float4 wd = *reinterpret_cast<const float4*>(&w0[32 + 8 * q + 4]);
    const float4 ba = *reinterpret_cast<const float4*>(&b0[4 * q]);
    const float4 bc = *reinterpret_cast<const float4*>(&b0[16 + 4 * q]);
    float wxs[8] = {wa.x, wa.z, wb.x, wb.z, wc.x, wc.z, wd.x, wd.z};
    float wys[8] = {wa.y, wa.w, wb.y, wb.w, wc.y, wc.w, wd.y, wd.w};
    float bbs[8] = {ba.x, ba.y, ba.z, ba.w, bc.x, bc.y, bc.z, bc.w};
#pragma unroll
    for (int j = 0; j < 8; ++j) {
        wxs[j] *= SINSCALE;
        wys[j] *= SINSCALE;
        bbs[j] *= SINSCALE;
    }

    // ---- build per-lane fragment table into LDS (once per wave) ----
    wtab[0][lane] = build_frag(w1, nl, q);
    wtab[1][lane] = build_frag(w1, 16 + nl, q);
    wtab[2][lane] = build_frag(w2, nl, q);
    wtab[3][lane] = build_frag(w2, 16 + nl, q);
    wtab[4][lane] = build_frag(w3, nl, q);
    wtab[5][lane] = build_frag(w3, 16 + nl, q);
    wtab[6][lane] = build_frag(w4, nl, q);
    wtab[7][lane] = build_frag(w4, 16 + nl, q);
    wtab[8][lane] = build_frag(w5, nl, q);
    wtab[9][lane]  = bias_frag_u(b1, 0, q);
    wtab[10][lane] = bias_frag_u(b1, 16, q);
    wtab[11][lane] = bias_frag_u(b2, 0, q);
    wtab[12][lane] = bias_frag_u(b2, 16, q);
    wtab[13][lane] = bias_frag_u(b3, 0, q);
    wtab[14][lane] = bias_frag_u(b3, 16, q);
    wtab[15][lane] = bias_frag_u(b4, 0, q);
    wtab[16][lane] = bias_frag_u(b4, 16, q);
    wtab[17][lane] = bias_frag_u(b5, 0, q);
    wtab[18][lane] = *reinterpret_cast<const uint4*>(&wf[0 * 16 + 4 * q]);
    wtab[19][lane] = *reinterpret_cast<const uint4*>(&wf[1 * 16 + 4 * q]);
    wtab[20][lane] = *reinterpret_cast<const uint4*>(&wf[2 * 16 + 4 * q]);

    // stop the compiler from forwarding LDS writes back into registers
    asm volatile("" ::: "memory");

    // ---- L0: args batch -> SB -> sin batch (64 independent sins pipeline)
    uint4 Bt[8];
    {
        float a[8][8];
#pragma unroll
        for (int t = 0; t < 8; ++t)
#pragma unroll
            for (int j = 0; j < 8; ++j)
                a[t][j] = fmaf(wxs[j], cxy[t].x, fmaf(wys[j], cxy[t].y, bbs[j]));
        __builtin_amdgcn_sched_barrier(0);
#pragma unroll
        for (int t = 0; t < 8; ++t) {
            float s[8];
#pragma unroll
            for (int j = 0; j < 8; ++j)
                s[j] = __builtin_amdgcn_sinf(a[t][j]);
            Bt[t].x = pk2(s[0], s[1]);
            Bt[t].y = pk2(s[2], s[3]);
            Bt[t].z = pk2(s[4], s[5]);
            Bt[t].w = pk2(s[6], s[7]);
        }
    }

    // ---- middle layers 1..4: [4 ds_read][16 MFMA] SB [64 sins + packs] ----
#pragma unroll
    for (int l = 0; l < 4; ++l) {
        S16 Ah0, Ah1;
        Ah0.u4 = wtab[2 * l][lane];
        Ah1.u4 = wtab[2 * l + 1][lane];
        WU bw0, bw1;
        bw0.u = wtab[9 + 2 * l][lane];
        bw1.u = wtab[10 + 2 * l][lane];
        const f32x4 bv0 = bw0.f;
        const f32x4 bv1 = bw1.f;
        f32x4 c0[8], c1[8];
#pragma unroll
        for (int t = 0; t < 8; ++t) {
            S16 B;
            B.u4 = Bt[t];
            c0[t] = __builtin_amdgcn_mfma_f32_16x16x32_f16(Ah0.h, B.h, bv0, 0, 0, 0);
            c1[t] = __builtin_amdgcn_mfma_f32_16x16x32_f16(Ah1.h, B.h, bv1, 0, 0, 0);
        }
        __builtin_amdgcn_sched_barrier(0);
#pragma unroll
        for (int t = 0; t < 8; ++t) {
            Bt[t].x = pk2(__builtin_amdgcn_sinf(c0[t][0]), __builtin_amdgcn_sinf(c0[t][1]));
            Bt[t].y = pk2(__builtin_amdgcn_sinf(c0[t][2]), __builtin_amdgcn_sinf(c0[t][3]));
            Bt[t].z = pk2(__builtin_amdgcn_sinf(c1[t][0]), __builtin_amdgcn_sinf(c1[t][1]));
            Bt[t].w = pk2(__builtin_amdgcn_sinf(c1[t][2]), __builtin_amdgcn_sinf(c1[t][3]));
        }
    }

    // ---- L5 (32->16) + final (16->3): [8 MFMA] SB [sins+reduce] ----
    {
        S16 Ah5;
        Ah5.u4 = wtab[8][lane];
        WU bw5;
        bw5.u = wtab[17][lane];
        const f32x4 bv5 = bw5.f;
        float4 wfl[3];
#pragma unroll
        for (int c = 0; c < 3; ++c) {
            WU w;
            w.u = wtab[18 + c][lane];
            wfl[c] = w.f4;
        }

        f32x4 c5[8];
#pragma unroll
        for (int t = 0; t < 8; ++t) {
            S16 B;
            B.u4 = Bt[t];
            c5[t] = __builtin_amdgcn_mfma_f32_16x16x32_f16(Ah5.h, B.h, bv5, 0, 0, 0);
        }
        __builtin_amdgcn_sched_barrier(0);

        float red[8][3];
#pragma unroll
        for (int t = 0; t < 8; ++t) {
            float h0 = __builtin_amdgcn_sinf(c5[t][0]);
            float h1 = __builtin_amdgcn_sinf(c5[t][1]);
            float h2 = __builtin_amdgcn_sinf(c5[t][2]);
            float h3 = __builtin_amdgcn_sinf(c5[t][3]);
#pragma unroll
            for (int c = 0; c < 3; ++c)
                red[t][c] = fmaf(wfl[c].x, h0, fmaf(wfl[c].y, h1,
                            fmaf(wfl[c].z, h2, wfl[c].w * h3)));
        }
        // butterfly over the 4 q-lanes sharing a point column
#pragma unroll
        for (int t = 0; t < 8; ++t)
#pragma unroll
            for (int c = 0; c < 3; ++c) {
                float v = red[t][c];
                v += __shfl_xor(v, 16, 64);
                v += __shfl_xor(v, 32, 64);
                red[t][c] = v;
            }
        // lane outputs two points: t=q (pts 0..63) and t=4+q (pts 64..127)
        float o0[3], o1[3];
#pragma unroll
        for (int c = 0; c < 3; ++c) {
            float v01 = (q & 1) ? red[1][c] : red[0][c];
            float v23 = (q & 1) ? red[3][c] : red[2][c];
            o0[c] = fast_sigmoid(((q & 2) ? v23 : v01) + bfin[c]);
            float w01 = (q & 1) ? red[5][c] : red[4][c];
            float w23 = (q & 1) ? red[7][c] : red[6][c];
            o1[c] = fast_sigmoid(((q & 2) ? w23 : w01) + bfin[c]);
        }
        const int p0 = pbase + 16 * q + nl;
        const int p1 = p0 + 64;
        if (p0 < n) {
            out[3 * p0 + 0] = o0[0];
            out[3 * p0 + 1] = o0[1];
            out[3 * p0 + 2] = o0[2];
        }
        if (p1 < n) {
            out[3 * p1 + 0] = o1[0];
            out[3 * p1 + 1] = o1[1];
            out[3 * p1 + 2] = o1[2];
        }
    }
}

extern "C" void kernel_launch(void* const* d_in, const int* in_sizes, int n_in,
                              void* d_out, int out_size, void* d_ws, size_t ws_size,
                              hipStream_t stream) {
    const float* coords = (const float*)d_in[0];
    const float* w0 = (const float*)d_in[1];
    const float* b0 = (const float*)d_in[2];
    const float* w1 = (const float*)d_in[3];
    const float* b1 = (const float*)d_in[4];
    const float* w2 = (const float*)d_in[5];
    const float* b2 = (const float*)d_in[6];
    const float* w3 = (const float*)d_in[7];
    const float* b3 = (const float*)d_in[8];
    const float* w4 = (const float*)d_in[9];
    const float* b4 = (const float*)d_in[10];
    const float* w5 = (const float*)d_in[11];
    const float* b5 = (const float*)d_in[12];
    const float* wf = (const float*)d_in[13];
    const float* bf = (const float*)d_in[14];
    float* out = (float*)d_out;

    const int n = in_sizes[0] / 2;

    siren_mfma<<<(n + 511) / 512, 256, 0, stream>>>(
        coords, w0, b0, w1, b1, w2, b2, w3, b3, w4, b4, w5, b5, wf, bf, out, n);
}

// Round 6
// 143.653 us; speedup vs baseline: 1.0730x; 1.0041x over previous
//
#include <hip/hip_runtime.h>
#include <hip/hip_fp16.h>

// SIREN, single fused kernel, register+LDS-resident, 64 points/wave.
// A=weights / B=activations: D[16 feat x 16 pt] = W[16,32] * X[32,16 pt].
// sigma(p)=16*((p>>2)&1)+4*(p>>3)+(p&3) k-permutation makes each lane's packed
// sin outputs BE the next layer's B-fragment (no shuffles in the loop).
// sigma(8q+j) = {4q+j (j<4), 16+4q+(j-4) (j>=4)} -> a lane's A-fragment is two
// aligned float4 loads from the raw weight matrix, packed with v_cvt_pkrtz.
// Weights single f16 (hi-only): adds ~2e-3 error, far under the 1.6e-2
// threshold. 30/(2pi) folded into weights/biases at load time.
//
// R17: MORE/SMALLER WAVES. Five rounds established: VALU busy TIME is a
// constant ~41us (sins ~75% of it at ~13.5cy effective); every scheduling
// structure (phase-split, sched_barrier, VGPR budget, LDS table) only moved
// the ~20us stall component and never beat R0's 58.4us; occupancy is stuck
// at ~3-3.5 waves/SIMD in ALL configs; per-wave latency (~28k cy) >> per-wave
// issue work (~6k cy). Conclusion: not enough independent waves to fill the
// 35% idle issue slots. This version halves the tile to 64 pts/wave (Bt[4]),
// DOUBLING wave count and halving each wave's latency footprint. The LDS
// weight table is now built COOPERATIVELY once per block (4 waves split 18
// slots + one __syncthreads), so the per-wave build overhead drops ~3.5x
// instead of doubling. wf rows leave the table (direct loads) -> LDS 18KB,
// 8 blocks/CU. Middle layers keep R0's serial per-t schedule (best measured).

#define SINSCALE 4.774648292756860f   // 30/(2*pi)

typedef __attribute__((ext_vector_type(8))) _Float16 half8;
typedef __attribute__((ext_vector_type(2))) __fp16 fp16x2;
typedef __attribute__((ext_vector_type(4))) float f32x4;

union S16 { uint4 u4; half8 h; };
union PK { fp16x2 h2; unsigned int u; };
union WU { uint4 u; f32x4 f; float4 f4; };

__device__ __forceinline__ float fast_sigmoid(float t) {
    float e = __builtin_amdgcn_exp2f(t * -1.4426950408889634f);
    return 1.0f / (1.0f + e);
}

__device__ __forceinline__ unsigned int pk2(float a, float b) {
    PK p; p.h2 = __builtin_amdgcn_cvt_pkrtz(a, b);
    return p.u;
}

// Build the sigma-permuted A-fragment (hi f16, RTZ) for feature rows m:
// slots j=0..3 <- W[m][4q+j]*S, j=4..7 <- W[m][16+4q+(j-4)]*S.
__device__ __forceinline__ uint4 build_frag(const float* __restrict__ W, int m, int q) {
    const float4 fa = *reinterpret_cast<const float4*>(&W[m * 32 + 4 * q]);
    const float4 fb = *reinterpret_cast<const float4*>(&W[m * 32 + 16 + 4 * q]);
    uint4 u;
    u.x = pk2(fa.x * SINSCALE, fa.y * SINSCALE);
    u.y = pk2(fa.z * SINSCALE, fa.w * SINSCALE);
    u.z = pk2(fb.x * SINSCALE, fb.y * SINSCALE);
    u.w = pk2(fb.z * SINSCALE, fb.w * SINSCALE);
    return u;
}

// Scaled bias vector (bit-pattern) for C/D rows 4q..4q+3 (+off)
__device__ __forceinline__ uint4 bias_frag_u(const float* __restrict__ b, int off, int q) {
    const float4 t = *reinterpret_cast<const float4*>(&b[off + 4 * q]);
    WU w;
    w.f = (f32x4){t.x * SINSCALE, t.y * SINSCALE, t.z * SINSCALE, t.w * SINSCALE};
    return w.u;
}

// LDS table slots: 0..7 = Af[layer l=s>>1][half s&1], 8 = Af5,
// 9..16 = bv[layer][half], 17 = bv5.
__global__ __launch_bounds__(256, 6) void siren_mfma(
    const float* __restrict__ coords,
    const float* __restrict__ w0, const float* __restrict__ b0,
    const float* __restrict__ w1, const float* __restrict__ b1,
    const float* __restrict__ w2, const float* __restrict__ b2,
    const float* __restrict__ w3, const float* __restrict__ b3,
    const float* __restrict__ w4, const float* __restrict__ b4,
    const float* __restrict__ w5, const float* __restrict__ b5,
    const float* __restrict__ wf, const float* __restrict__ bfin,
    float* __restrict__ out, int n) {
    const int lane = (int)(threadIdx.x & 63);
    const int q = lane >> 4;
    const int nl = lane & 15;
    const int wave = (int)(threadIdx.x >> 6);
    const int pbase = blockIdx.x * 256 + wave * 64;

    __shared__ uint4 wtab[18][64];

    // ---- coords early: 4 independent global_load_dwordx2 in flight ----
    float2 cxy[4];
#pragma unroll
    for (int t = 0; t < 4; ++t) {
        int ptc = min(pbase + 16 * t + nl, n - 1);
        cxy[t] = reinterpret_cast<const float2*>(coords)[ptc];
    }

    // ---- cooperative LDS weight-table build: wave w does slots w, w+4, ...
    {
        const float* Ws[5] = {w1, w2, w3, w4, w5};
        const float* Bsb[5] = {b1, b2, b3, b4, b5};
        for (int s = wave; s < 18; s += 4) {
            uint4 v;
            if (s < 8) {
                v = build_frag(Ws[s >> 1], 16 * (s & 1) + nl, q);
            } else if (s == 8) {
                v = build_frag(w5, nl, q);
            } else if (s < 17) {
                v = bias_frag_u(Bsb[(s - 9) >> 1], 16 * ((s - 9) & 1), q);
            } else {
                v = bias_frag_u(b5, 0, q);
            }
            wtab[s][lane] = v;
        }
    }

    // ---- L0 constants (2 -> 32 in B-frag feature order sigma(8q+j)) ----
    const float4 wa = *reinterpret_cast<const float4*>(&w0[8 * q]);
    const float4 wb = *reinterpret_cast<const float4*>(&w0[8 * q + 4]);
    const float4 wc = *reinterpret_cast<const float4*>(&w0[32 + 8 * q]);
    const float4 wd = *reinterpret_cast<const float4*>(&w0[32 + 8 * q + 4]);
    const float4 ba = *reinterpret_cast<const float4*>(&b0[4 * q]);
    const float4 bc = *reinterpret_cast<const float4*>(&b0[16 + 4 * q]);
    float wxs[8] = {wa.x, wa.z, wb.x, wb.z, wc.x, wc.z, wd.x, wd.z};
    float wys[8] = {wa.y, wa.w, wb.y, wb.w, wc.y, wc.w, wd.y, wd.w};
    float bbs[8] = {ba.x, ba.y, ba.z, ba.w, bc.x, bc.y, bc.z, bc.w};
#pragma unroll
    for (int j = 0; j < 8; ++j) {
        wxs[j] *= SINSCALE;
        wys[j] *= SINSCALE;
        bbs[j] *= SINSCALE;
    }

    __syncthreads();

    // ---- L0: sin(w0x*x + w0y*y + b0) in B-frag layout ----
    uint4 Bt[4];
#pragma unroll
    for (int t = 0; t < 4; ++t) {
        float s[8];
#pragma unroll
        for (int j = 0; j < 8; ++j)
            s[j] = __builtin_amdgcn_sinf(fmaf(wxs[j], cxy[t].x, fmaf(wys[j], cxy[t].y, bbs[j])));
        Bt[t].x = pk2(s[0], s[1]);
        Bt[t].y = pk2(s[2], s[3]);
        Bt[t].z = pk2(s[4], s[5]);
        Bt[t].w = pk2(s[6], s[7]);
    }

    // ---- middle layers 1..4: A-frags + biases from LDS (ds_read_b128) ----
#pragma unroll
    for (int l = 0; l < 4; ++l) {
        S16 Ah0, Ah1;
        Ah0.u4 = wtab[2 * l][lane];
        Ah1.u4 = wtab[2 * l + 1][lane];
        WU bw0, bw1;
        bw0.u = wtab[9 + 2 * l][lane];
        bw1.u = wtab[10 + 2 * l][lane];
        const f32x4 bv0 = bw0.f;
        const f32x4 bv1 = bw1.f;
#pragma unroll
        for (int t = 0; t < 4; ++t) {
            S16 B;
            B.u4 = Bt[t];
            f32x4 c0 = __builtin_amdgcn_mfma_f32_16x16x32_f16(Ah0.h, B.h, bv0, 0, 0, 0);
            f32x4 c1 = __builtin_amdgcn_mfma_f32_16x16x32_f16(Ah1.h, B.h, bv1, 0, 0, 0);
            Bt[t].x = pk2(__builtin_amdgcn_sinf(c0[0]), __builtin_amdgcn_sinf(c0[1]));
            Bt[t].y = pk2(__builtin_amdgcn_sinf(c0[2]), __builtin_amdgcn_sinf(c0[3]));
            Bt[t].z = pk2(__builtin_amdgcn_sinf(c1[0]), __builtin_amdgcn_sinf(c1[1]));
            Bt[t].w = pk2(__builtin_amdgcn_sinf(c1[2]), __builtin_amdgcn_sinf(c1[3]));
        }
    }

    // ---- L5 (32->16) + final (16->3): registers + shfl butterfly ----
    {
        S16 Ah5;
        Ah5.u4 = wtab[8][lane];
        WU bw5;
        bw5.u = wtab[17][lane];
        const f32x4 bv5 = bw5.f;
        float4 wfl[3];
#pragma unroll
        for (int c = 0; c < 3; ++c)
            wfl[c] = *reinterpret_cast<const float4*>(&wf[c * 16 + 4 * q]);

        float red[4][3];
#pragma unroll
        for (int t = 0; t < 4; ++t) {
            S16 B;
            B.u4 = Bt[t];
            f32x4 c5 = __builtin_amdgcn_mfma_f32_16x16x32_f16(Ah5.h, B.h, bv5, 0, 0, 0);
            float h0 = __builtin_amdgcn_sinf(c5[0]);
            float h1 = __builtin_amdgcn_sinf(c5[1]);
            float h2 = __builtin_amdgcn_sinf(c5[2]);
            float h3 = __builtin_amdgcn_sinf(c5[3]);
#pragma unroll
            for (int c = 0; c < 3; ++c)
                red[t][c] = fmaf(wfl[c].x, h0, fmaf(wfl[c].y, h1,
                            fmaf(wfl[c].z, h2, wfl[c].w * h3)));
        }
        // butterfly over the 4 q-lanes sharing a point column
#pragma unroll
        for (int t = 0; t < 4; ++t)
#pragma unroll
            for (int c = 0; c < 3; ++c) {
                float v = red[t][c];
                v += __shfl_xor(v, 16, 64);
                v += __shfl_xor(v, 32, 64);
                red[t][c] = v;
            }
        // lane outputs one point: t selected by its own q
        float o0[3];
#pragma unroll
        for (int c = 0; c < 3; ++c) {
            float v01 = (q & 1) ? red[1][c] : red[0][c];
            float v23 = (q & 1) ? red[3][c] : red[2][c];
            o0[c] = fast_sigmoid(((q & 2) ? v23 : v01) + bfin[c]);
        }
        const int p0 = pbase + 16 * q + nl;
        if (p0 < n) {
            out[3 * p0 + 0] = o0[0];
            out[3 * p0 + 1] = o0[1];
            out[3 * p0 + 2] = o0[2];
        }
    }
}

extern "C" void kernel_launch(void* const* d_in, const int* in_sizes, int n_in,
                              void* d_out, int out_size, void* d_ws, size_t ws_size,
                              hipStream_t stream) {
    const float* coords = (const float*)d_in[0];
    const float* w0 = (const float*)d_in[1];
    const float* b0 = (const float*)d_in[2];
    const float* w1 = (const float*)d_in[3];
    const float* b1 = (const float*)d_in[4];
    const float* w2 = (const float*)d_in[5];
    const float* b2 = (const float*)d_in[6];
    const float* w3 = (const float*)d_in[7];
    const float* b3 = (const float*)d_in[8];
    const float* w4 = (const float*)d_in[9];
    const float* b4 = (const float*)d_in[10];
    const float* w5 = (const float*)d_in[11];
    const float* b5 = (const float*)d_in[12];
    const float* wf = (const float*)d_in[13];
    const float* bf = (const float*)d_in[14];
    float* out = (float*)d_out;

    const int n = in_sizes[0] / 2;

    // 64 points per wave, 4 waves per block -> 256 points per block.
    siren_mfma<<<(n + 255) / 256, 256, 0, stream>>>(
        coords, w0, b0, w1, b1, w2, b2, w3, b3, w4, b4, w5, b5, wf, bf, out, n);
}